// Round 1
// baseline (128.737 us; speedup 1.0000x reference)
//
#include <hip/hip_runtime.h>
#include <hip/hip_bf16.h>
#include <cstdint>

// Problem constants (fixed by reference)
#define SEQ   2048
#define CH    1024
#define NHEAD 16
#define HDIM  64
#define KSZ   7
#define NCOL  112      // NHEAD * KSZ
#define PADW  3        // KSZ/2

// Tiling
#define BM       32    // sequence rows per block
#define BK       64    // K chunk staged per iteration
#define NTHREADS 256   // 4 waves
#define LDA_STR  72    // LDS stride (bf16 elems) for A tile; 72*2B=144B -> 4-bank shift/row
#define LDB_STR  72    // LDS stride for Bt tile
#define LDK_STR  113   // LDS stride (floats) for predicted kernels

typedef __bf16 v8bf __attribute__((ext_vector_type(8)));
typedef float  v4f  __attribute__((ext_vector_type(4)));

__global__ __launch_bounds__(NTHREADS)
void dynconv_fused(const float* __restrict__ x,
                   const float* __restrict__ Wp,
                   const float* __restrict__ bp,
                   float* __restrict__ out)
{
    __shared__ __bf16 ldsA[BM * LDA_STR];     //  4,608 B
    __shared__ __bf16 ldsB[NCOL * LDB_STR];   // 16,128 B
    __shared__ float  ldsK[BM * LDK_STR];     // 14,464 B

    const int tid = threadIdx.x;
    const int bb  = blockIdx.x;        // 0..255
    const int b   = bb >> 6;           // 64 chunks of 32 rows per batch
    const int s0  = (bb & 63) << 5;    // starting sequence row

    const int wave = tid >> 6;
    const int lane = tid & 63;
    const int lq   = lane >> 4;        // quad 0..3
    const int lm   = lane & 15;

    // wave -> (row stripe, col-tile range): waves 0,1 -> tiles 0..3 ; waves 2,3 -> tiles 4..6
    const int stripe = wave & 1;
    const int t0     = (wave >> 1) * 4;
    const int nt     = (wave >> 1) ? 3 : 4;

    v4f acc[4];
    acc[0] = (v4f){0.f,0.f,0.f,0.f};
    acc[1] = (v4f){0.f,0.f,0.f,0.f};
    acc[2] = (v4f){0.f,0.f,0.f,0.f};
    acc[3] = (v4f){0.f,0.f,0.f,0.f};

    const float* xbase = x + (size_t)b * SEQ * CH;
    const float* xrow0 = xbase + (size_t)s0 * CH;

    // ---------------- Phase 1: kernels = x @ W_pred (bf16 MFMA, fp32 acc) ----------------
    for (int kc = 0; kc < CH; kc += BK) {
        // Stage A: 32 rows x 64 k as bf16. 512 float4 loads, 2 per thread, coalesced.
        #pragma unroll
        for (int j = 0; j < 2; ++j) {
            const int q  = j * NTHREADS + tid;     // 0..511
            const int r  = q >> 4;                 // 0..31
            const int k4 = (q & 15) << 2;          // 0..60
            const v4f v = *(const v4f*)(xrow0 + (size_t)r * CH + kc + k4);
            __bf16* d = &ldsA[r * LDA_STR + k4];
            d[0] = (__bf16)v.x; d[1] = (__bf16)v.y; d[2] = (__bf16)v.z; d[3] = (__bf16)v.w;
        }
        // Stage B transposed: W[kc+kk][n] -> ldsB[n][kk]. 1792 float4 loads, 7/thread, coalesced.
        #pragma unroll
        for (int j = 0; j < 7; ++j) {
            const int q  = j * NTHREADS + tid;     // 0..1791
            const int kk = q / 28;                 // 0..63
            const int n4 = (q - kk * 28) << 2;     // 0..108
            const v4f v = *(const v4f*)(Wp + (size_t)(kc + kk) * NCOL + n4);
            ldsB[(n4 + 0) * LDB_STR + kk] = (__bf16)v.x;
            ldsB[(n4 + 1) * LDB_STR + kk] = (__bf16)v.y;
            ldsB[(n4 + 2) * LDB_STR + kk] = (__bf16)v.z;
            ldsB[(n4 + 3) * LDB_STR + kk] = (__bf16)v.w;
        }
        __syncthreads();

        #pragma unroll
        for (int ks = 0; ks < BK; ks += 32) {
            // A frag: A[m=lm][k = ks + lq*8 + j]  (16B aligned: 144B row stride, 16B quad offset)
            const v8bf afrag = *(const v8bf*)&ldsA[(stripe * 16 + lm) * LDA_STR + ks + lq * 8];
            for (int t = 0; t < nt; ++t) {
                // B frag: B[k][n=lm] read from transposed ldsB[n][k]
                const v8bf bfrag = *(const v8bf*)&ldsB[((t0 + t) * 16 + lm) * LDB_STR + ks + lq * 8];
                acc[t] = __builtin_amdgcn_mfma_f32_16x16x32_bf16(afrag, bfrag, acc[t], 0, 0, 0);
            }
        }
        __syncthreads();
    }

    // Epilogue: bias, scatter predicted kernels to LDS.
    // C/D layout: col = lane&15, row = (lane>>4)*4 + reg  [m89/m91 verified]
    for (int t = 0; t < nt; ++t) {
        const int col  = (t0 + t) * 16 + lm;
        const float bias = bp[col];
        #pragma unroll
        for (int r = 0; r < 4; ++r) {
            const int row = stripe * 16 + lq * 4 + r;
            ldsK[row * LDK_STR + col] = acc[t][r] + bias;
        }
    }
    __syncthreads();

    // ---------------- Phase 2: dynamic conv ----------------
    // thread t owns channels [4t, 4t+3]; head h = t>>4 (64 ch per head).
    const int h  = tid >> 4;
    const int c4 = tid << 2;
    float* orow0 = out + ((size_t)b * SEQ + s0) * CH;

    // rolling 7-row register window: at iter r, win[i] = x[s0 + r - 3 + i][c4..c4+3]
    v4f win[7];
    #pragma unroll
    for (int i = 0; i < 6; ++i) {
        const int sg = s0 - PADW + i;
        win[i] = (sg >= 0 && sg < SEQ) ? *(const v4f*)(xbase + (size_t)sg * CH + c4)
                                       : (v4f){0.f,0.f,0.f,0.f};
    }
    win[6] = (v4f){0.f,0.f,0.f,0.f};

    #pragma unroll
    for (int r = 0; r < BM; ++r) {
        const int sg = s0 + r + PADW;           // newest row entering window
        win[6] = (sg < SEQ) ? *(const v4f*)(xbase + (size_t)sg * CH + c4)
                            : (v4f){0.f,0.f,0.f,0.f};

        const float* kp = &ldsK[r * LDK_STR + h * KSZ];
        v4f a = (v4f){0.f,0.f,0.f,0.f};
        #pragma unroll
        for (int i = 0; i < 7; ++i) {
            a += kp[i] * win[i];
        }
        *(v4f*)(orow0 + (size_t)r * CH + c4) = a;

        #pragma unroll
        for (int i = 0; i < 6; ++i) win[i] = win[i + 1];
    }
}

extern "C" void kernel_launch(void* const* d_in, const int* in_sizes, int n_in,
                              void* d_out, int out_size, void* d_ws, size_t ws_size,
                              hipStream_t stream) {
    const float* x  = (const float*)d_in[0];
    const float* Wp = (const float*)d_in[1];
    const float* bp = (const float*)d_in[2];
    float* out = (float*)d_out;
    dynconv_fused<<<dim3(256), dim3(NTHREADS), 0, stream>>>(x, Wp, bp, out);
}

// Round 2
// 105.216 us; speedup vs baseline: 1.2236x; 1.2236x over previous
//
#include <hip/hip_runtime.h>
#include <hip/hip_bf16.h>
#include <cstdint>

// Problem constants (fixed by reference)
#define SEQ   2048
#define CH    1024
#define NHEAD 16
#define KSZ   7
#define NCOL  112      // NHEAD * KSZ
#define PADW  3        // KSZ/2

// Tiling
#define BM       16    // sequence rows per block -> 512 blocks
#define NTHREADS 256   // 4 waves
#define LDK_STR  113   // LDS stride (floats) for predicted kernels
#define NKSTEP   32    // CH / 32 (K-steps of the 16x16x32 MFMA)
#define WS_FRAG_BYTES (NKSTEP * 7 * 64 * 16)   // 229,376 B of pre-packed B-frags

typedef __bf16 v8bf __attribute__((ext_vector_type(8)));
typedef float  v4f  __attribute__((ext_vector_type(4)));

// ---------------------------------------------------------------------------
// Prologue: convert W_pred (fp32 [1024][112]) to bf16 packed in MFMA B-frag
// order: ws[(((s*7 + t)*64 + lane)*8 + j)] = W[k = s*32 + (lane>>4)*8 + j]
//                                             [n = t*16 + (lane&15)]
// so the GEMM loads each B-frag as one coalesced dwordx4 per lane.
// ---------------------------------------------------------------------------
__global__ __launch_bounds__(256)
void prep_w(const float* __restrict__ Wp, __bf16* __restrict__ wsB) {
    const int g  = blockIdx.x * 256 + threadIdx.x;   // 0..114687
    const int j  = g & 7;
    const int l  = (g >> 3) & 63;
    const int st = g >> 9;            // s*7 + t, 0..223
    const int s  = st / 7;
    const int t  = st - s * 7;
    const int k  = s * 32 + (l >> 4) * 8 + j;
    const int n  = t * 16 + (l & 15);
    wsB[g] = (__bf16)Wp[k * NCOL + n];
}

// ---------------------------------------------------------------------------
// Fused kernel: per block, 16 seq rows of one batch.
// Phase 1: kernels = x @ W (bf16 MFMA, barrier-free K-loop, B-frags from ws).
// Phase 2: dynamic conv with a full 22-row register window.
// ---------------------------------------------------------------------------
template <bool PRE>
__global__ __launch_bounds__(NTHREADS, 2)
void dynconv_fused(const float* __restrict__ x,
                   const float* __restrict__ Wp,
                   const float* __restrict__ bp,
                   const __bf16* __restrict__ wsB,
                   float* __restrict__ out)
{
    __shared__ float ldsK[BM * LDK_STR];   // 7,232 B

    const int tid  = threadIdx.x;
    const int bb   = blockIdx.x;          // 0..511
    const int b    = bb >> 7;             // 128 blocks per batch
    const int s0   = (bb & 127) << 4;     // starting sequence row

    const int wave = tid >> 6;
    const int lane = tid & 63;
    const int lq   = lane >> 4;           // quad 0..3
    const int lm   = lane & 15;

    const float* xbase = x + (size_t)b * SEQ * CH;

    // ---- Phase 1: GEMM ----
    // Wave w owns n-tiles {2w, 2w+1}; wave 3 duplicates tile 6 (benign).
    const int tile0 = wave * 2;
    const int tile1 = (wave < 3) ? wave * 2 + 1 : 6;

    v4f acc0 = (v4f){0.f, 0.f, 0.f, 0.f};
    v4f acc1 = (v4f){0.f, 0.f, 0.f, 0.f};

    // A-frag base: lane (lq,lm) reads x[s0+lm][k = s*32 + lq*8 .. +7]
    const float* arow = xbase + (size_t)(s0 + lm) * CH + lq * 8;

    #pragma unroll 8
    for (int s = 0; s < NKSTEP; ++s) {
        const float* p = arow + s * 32;
        const v4f v0 = *(const v4f*)p;
        const v4f v1 = *(const v4f*)(p + 4);
        v8bf af;
        af[0] = (__bf16)v0.x; af[1] = (__bf16)v0.y;
        af[2] = (__bf16)v0.z; af[3] = (__bf16)v0.w;
        af[4] = (__bf16)v1.x; af[5] = (__bf16)v1.y;
        af[6] = (__bf16)v1.z; af[7] = (__bf16)v1.w;

        v8bf bf0, bf1;
        if (PRE) {
            bf0 = *(const v8bf*)&wsB[(size_t)((s * 7 + tile0) * 64 + lane) * 8];
            bf1 = *(const v8bf*)&wsB[(size_t)((s * 7 + tile1) * 64 + lane) * 8];
        } else {
            #pragma unroll
            for (int j = 0; j < 8; ++j) {
                const int k = s * 32 + lq * 8 + j;
                bf0[j] = (__bf16)Wp[k * NCOL + tile0 * 16 + lm];
                bf1[j] = (__bf16)Wp[k * NCOL + tile1 * 16 + lm];
            }
        }
        acc0 = __builtin_amdgcn_mfma_f32_16x16x32_bf16(af, bf0, acc0, 0, 0, 0);
        acc1 = __builtin_amdgcn_mfma_f32_16x16x32_bf16(af, bf1, acc1, 0, 0, 0);
    }

    // Epilogue: bias + scatter to ldsK.
    // C/D layout: col = lane&15, row = (lane>>4)*4 + reg  [m89/m91 verified]
    {
        const int ct0 = tile0 * 16 + lm;
        const float bias0 = bp[ct0];
        #pragma unroll
        for (int r = 0; r < 4; ++r)
            ldsK[(lq * 4 + r) * LDK_STR + ct0] = acc0[r] + bias0;
        if (wave < 3) {
            const int ct1 = tile1 * 16 + lm;
            const float bias1 = bp[ct1];
            #pragma unroll
            for (int r = 0; r < 4; ++r)
                ldsK[(lq * 4 + r) * LDK_STR + ct1] = acc1[r] + bias1;
        }
    }

    // ---- Phase 2: dynamic conv ----
    // Thread owns channels [4*tid, 4*tid+3]; head h = tid>>4.
    // Preload the full 22-row window into registers BEFORE the barrier so the
    // barrier wait overlaps the load latency.
    const int h  = tid >> 4;
    const int c4 = tid << 2;

    v4f win[BM + 6];
    #pragma unroll
    for (int i = 0; i < BM + 6; ++i) {
        const int sg = s0 - PADW + i;
        win[i] = (sg >= 0 && sg < SEQ)
                     ? *(const v4f*)(xbase + (size_t)sg * CH + c4)
                     : (v4f){0.f, 0.f, 0.f, 0.f};
    }

    __syncthreads();

    float* orow = out + ((size_t)b * SEQ + s0) * CH + c4;
    #pragma unroll
    for (int r = 0; r < BM; ++r) {
        const float* kp = &ldsK[r * LDK_STR + h * KSZ];
        v4f a = (v4f){0.f, 0.f, 0.f, 0.f};
        #pragma unroll
        for (int i = 0; i < KSZ; ++i) {
            a += kp[i] * win[r + i];
        }
        *(v4f*)(orow + (size_t)r * CH) = a;
    }
}

extern "C" void kernel_launch(void* const* d_in, const int* in_sizes, int n_in,
                              void* d_out, int out_size, void* d_ws, size_t ws_size,
                              hipStream_t stream) {
    const float* x  = (const float*)d_in[0];
    const float* Wp = (const float*)d_in[1];
    const float* bp = (const float*)d_in[2];
    float* out = (float*)d_out;

    if (ws_size >= (size_t)WS_FRAG_BYTES) {
        __bf16* wsB = (__bf16*)d_ws;
        prep_w<<<dim3(448), dim3(256), 0, stream>>>(Wp, wsB);
        dynconv_fused<true><<<dim3(512), dim3(NTHREADS), 0, stream>>>(x, Wp, bp, wsB, out);
    } else {
        dynconv_fused<false><<<dim3(512), dim3(NTHREADS), 0, stream>>>(x, Wp, bp, nullptr, out);
    }
}